// Round 12
// baseline (126.067 us; speedup 1.0000x reference)
//
#include <hip/hip_runtime.h>

typedef __attribute__((ext_vector_type(4))) float f32x4;
typedef __attribute__((ext_vector_type(8))) short s16x8;
typedef __attribute__((ext_vector_type(4))) unsigned int u32x4;

#define MFMA_16x16x32_BF16 __builtin_amdgcn_mfma_f32_16x16x32_bf16

__device__ __forceinline__ unsigned short f2bf(float f) {
  unsigned int u = __builtin_bit_cast(unsigned int, f);
  unsigned int r = (u + 0x7FFFu + ((u >> 16) & 1u)) >> 16;  // RNE
  return (unsigned short)r;
}

__device__ __forceinline__ unsigned int cvt_pk_bf16(float lo, float hi) {
  unsigned int r;
  asm("v_cvt_pk_bf16_f32 %0, %1, %2" : "=v"(r) : "v"(lo), "v"(hi));
  return r;
}

__device__ __forceinline__ float fexp2(float x) {
#if __has_builtin(__builtin_amdgcn_exp2f)
  return __builtin_amdgcn_exp2f(x);
#else
  float r;
  asm("v_exp_f32 %0, %1" : "=v"(r) : "v"(x));
  return r;
#endif
}

// Fused LDS barrier: waitcnt + s_barrier in ONE asm with memory clobber.
// Leaves vmcnt (global loads/stores) in flight.
__device__ __forceinline__ void lds_barrier() {
  asm volatile("s_waitcnt lgkmcnt(0)\n\ts_barrier" ::: "memory");
}

#define RCP __builtin_amdgcn_rcpf
#define L2E 1.442695040888963f   // 1/ln2
#define L2E2 2.885390081777927f  // 2/ln2

// ---- kernel 0: pack Wc = [W_ih | W_hh] (512 x 256) -> bf16, PRE-SCALED ----
// (i,f,o: -1/ln2; g: 2/ln2) so MFMA output is directly exp2-ready.
__global__ __launch_bounds__(256) void pack_kernel(
    const float* __restrict__ Wih, const float* __restrict__ Whh,
    const float* __restrict__ bih, const float* __restrict__ bhh,
    unsigned short* __restrict__ Wc, float* __restrict__ biasC) {
  int i = blockIdx.x * 256 + threadIdx.x;  // 32768 chunks of 4 elems
  int col = i >> 6;
  int k4 = (i & 63) << 2;
  const float s = ((i >> 13) == 2) ? L2E2 : -L2E;  // gate = col>>7 = i>>13
  const float* src = (k4 < 128) ? (Wih + col * 128 + k4)
                                : (Whh + col * 128 + (k4 - 128));
  const float4 v = *reinterpret_cast<const float4*>(src);
  ushort4 u;
  u.x = f2bf(v.x * s); u.y = f2bf(v.y * s);
  u.z = f2bf(v.z * s); u.w = f2bf(v.w * s);
  *reinterpret_cast<ushort4*>(Wc + (size_t)col * 256 + k4) = u;
  if (i < 512) {
    const float b = bih[i] + bhh[i];
    biasC[i] = ((i >> 7) == 2 ? L2E2 : -L2E) * b;
  }
}

// ---- kernel A: attn[b,:] = softmax_d( sum_t x[b,t,:] * wt[t] ) ----
__global__ __launch_bounds__(64) void attn_kernel(
    const float* __restrict__ x, const float* __restrict__ Wattn,
    float* __restrict__ attn) {
  const int b = blockIdx.x;
  const int l = threadIdx.x;  // 0..63
  const float* xb = x + (size_t)b * 64 * 128;
  const float wtl = Wattn[256 + l];
  float s0 = 0.f, s1 = 0.f;
  for (int t = 0; t < 64; ++t) {
    float w = __shfl(wtl, t, 64);
    s0 = fmaf(xb[t * 128 + l], w, s0);
    s1 = fmaf(xb[t * 128 + 64 + l], w, s1);
  }
  float m = fmaxf(s0, s1);
  for (int off = 32; off; off >>= 1) m = fmaxf(m, __shfl_xor(m, off, 64));
  float e0 = __expf(s0 - m), e1 = __expf(s1 - m);
  float sum = e0 + e1;
  for (int off = 32; off; off >>= 1) sum += __shfl_xor(sum, off, 64);
  float inv = RCP(sum);
  attn[(size_t)b * 128 + l] = e0 * inv;
  attn[(size_t)b * 128 + 64 + l] = e1 * inv;
}

// ---- kernel B: persistent LSTM, FAT-WAVE variant ----
// 256 thr = 4 waves (1/SIMD, launch_bounds(256,1) -> 512 VGPR budget),
// 16 rows/block, grid 256. Wave w owns 128 gate-cols:
// {g*128 + w*32 + jj*16 + l15 : g=0..3, jj=0..1} -> 8 acc tiles.
// bfr = 4x2x8 frags = 256 VGPR, loaded once. Per step each wave reads the
// 16x256 A-matrix ONCE (8 ds_read_b128) -> LDS traffic halves vs 8 waves
// (32KB vs 64KB/step), bank conflicts halve, barrier syncs 4 waves not 8.
// 2-ahead pipeline as R11: W-MFMA(T+1) first, H-MFMA(T), stage w_in(T+2),
// EW(T) (8 cells/lane), h->LDS, out-stores. ONE fused lds_barrier/step.
// LDS: wbuf0@0, wbuf1@4096, hbuf0@8192, hbuf1@12288; swizzle ^(row&7)<<4.
__global__ __launch_bounds__(256, 1) void lstm_kernel(
    const float* __restrict__ x, const unsigned short* __restrict__ Wc,
    const float* __restrict__ biasC, const float* __restrict__ attn,
    float* __restrict__ out) {
  __shared__ __attribute__((aligned(16))) char sAb[16384];

  const int tid = threadIdx.x;
  const int l = tid & 63;
  const int w = tid >> 6;   // 0..3
  const int l15 = l & 15;
  const int khi = l >> 4;   // 0..3
  const int rowBase = blockIdx.x * 16;

  // ---- B fragments into registers (once): 4 gates x 2 jj x 8 kt ----
  s16x8 bfr[4][2][8];
  float bias2[4][2];
#pragma unroll
  for (int g = 0; g < 4; ++g)
#pragma unroll
    for (int jj = 0; jj < 2; ++jj) {
      const int col = g * 128 + w * 32 + jj * 16 + l15;
      const unsigned short* p = Wc + (size_t)col * 256 + khi * 8;
#pragma unroll
      for (int kt = 0; kt < 8; ++kt)
        bfr[g][jj][kt] = *reinterpret_cast<const s16x8*>(p + kt * 32);
      bias2[g][jj] = biasC[col];
    }

  // ---- staging role: thread -> (row r_st, 8 cols at c_st) ----
  const int r_st = tid >> 4;          // 0..15
  const int c_st = (tid & 15) << 3;   // 0..120
  const float4 at0 =
      *reinterpret_cast<const float4*>(attn + (size_t)(rowBase + r_st) * 128 + c_st);
  const float4 at1 =
      *reinterpret_cast<const float4*>(attn + (size_t)(rowBase + r_st) * 128 + c_st + 4);
  const float* xrow = x + (size_t)(rowBase + r_st) * 8192 + c_st;
  // 16B-aligned staging slot; swizzle unit is 16B so one b128 write fits
  char* stgW = sAb + r_st * 256 + (((c_st) << 1) ^ ((r_st & 7) << 4));

  // zero hbuf1 (h(-1) = 0; iter 0 reads hbuf1): 256 thr x 16B = 4KB
  {
    u32x4 z = {0u, 0u, 0u, 0u};
    *reinterpret_cast<u32x4*>(sAb + 12288 + tid * 16) = z;
  }

  // stage w_in(0) -> wbuf0, w_in(1) -> wbuf1
  {
    const float4 a0 = *reinterpret_cast<const float4*>(xrow);
    const float4 a1 = *reinterpret_cast<const float4*>(xrow + 4);
    const float4 b0 = *reinterpret_cast<const float4*>(xrow + 128);
    const float4 b1 = *reinterpret_cast<const float4*>(xrow + 132);
    u32x4 u0, u1;
    u0[0] = cvt_pk_bf16(a0.x * at0.x, a0.y * at0.y);
    u0[1] = cvt_pk_bf16(a0.z * at0.z, a0.w * at0.w);
    u0[2] = cvt_pk_bf16(a1.x * at1.x, a1.y * at1.y);
    u0[3] = cvt_pk_bf16(a1.z * at1.z, a1.w * at1.w);
    u1[0] = cvt_pk_bf16(b0.x * at0.x, b0.y * at0.y);
    u1[1] = cvt_pk_bf16(b0.z * at0.z, b0.w * at0.w);
    u1[2] = cvt_pk_bf16(b1.x * at1.x, b1.y * at1.y);
    u1[3] = cvt_pk_bf16(b1.z * at1.z, b1.w * at1.w);
    *reinterpret_cast<u32x4*>(stgW) = u0;
    *reinterpret_cast<u32x4*>(stgW + 4096) = u1;
  }
  float4 xE0 = *reinterpret_cast<const float4*>(xrow + 2 * 128);      // x(2)
  float4 xE1 = *reinterpret_cast<const float4*>(xrow + 2 * 128 + 4);
  float4 xO0 = *reinterpret_cast<const float4*>(xrow + 3 * 128);      // x(3)
  float4 xO1 = *reinterpret_cast<const float4*>(xrow + 3 * 128 + 4);

  // ---- MFMA read pointers (base = buf0; add RW/RH per parity) ----
  const char* aw[4];
  const char* ah[4];
#pragma unroll
  for (int k = 0; k < 4; ++k) {
    aw[k] = sAb + l15 * 256 + ((k * 64 + khi * 16) ^ ((l15 & 7) << 4));
    ah[k] = aw[k] + 8192;
  }
  // h-write pointers (base = hbuf0): 8 b16 slots
  char* hw[2][4];
#pragma unroll
  for (int jj = 0; jj < 2; ++jj)
#pragma unroll
    for (int rr = 0; rr < 4; ++rr) {
      const int row = khi * 4 + rr;
      const int d = w * 32 + jj * 16 + l15;
      hw[jj][rr] = sAb + 8192 + row * 256 + ((d << 1) ^ ((row & 7) << 4));
    }

  float c4[2][4] = {{0.f, 0.f, 0.f, 0.f}, {0.f, 0.f, 0.f, 0.f}};
  float* outP = out + (size_t)(rowBase + khi * 4) * 8192 + w * 32 + l15;

  lds_barrier();

  // pre-loop: accA = bias + W-part(0) (reads wbuf0)
  f32x4 accA[4][2], accB[4][2];
#pragma unroll
  for (int g = 0; g < 4; ++g)
#pragma unroll
    for (int jj = 0; jj < 2; ++jj)
      accA[g][jj] = f32x4{bias2[g][jj], bias2[g][jj], bias2[g][jj], bias2[g][jj]};
#pragma unroll
  for (int k = 0; k < 4; ++k) {
    const s16x8 af = *reinterpret_cast<const s16x8*>(aw[k]);
#pragma unroll
    for (int g = 0; g < 4; ++g)
#pragma unroll
      for (int jj = 0; jj < 2; ++jj)
        accA[g][jj] = MFMA_16x16x32_BF16(af, bfr[g][jj][k], accA[g][jj], 0, 0, 0);
  }

  lds_barrier();  // close pre-loop reads of wbuf0 before STEP0 overwrites it

#define STEP(T, ACCC, ACCN, RW, RH, SW, WH, XV0, XV1)                          \
  {                                                                            \
    /* fragment loads upfront: fw (stable buffer), fh (fresh h) */             \
    s16x8 fw[4], fh[4];                                                        \
    _Pragma("unroll") for (int k = 0; k < 4; ++k)                              \
        fw[k] = *reinterpret_cast<const s16x8*>(aw[k] + (RW));                 \
    _Pragma("unroll") for (int k = 0; k < 4; ++k)                              \
        fh[k] = *reinterpret_cast<const s16x8*>(ah[k] + (RH));                 \
    /* W-MFMA(T+1) into ACCN */                                                \
    _Pragma("unroll") for (int g = 0; g < 4; ++g)                              \
        _Pragma("unroll") for (int jj = 0; jj < 2; ++jj)                       \
            ACCN[g][jj] = f32x4{bias2[g][jj], bias2[g][jj],                    \
                                bias2[g][jj], bias2[g][jj]};                   \
    _Pragma("unroll") for (int k = 0; k < 4; ++k)                              \
        _Pragma("unroll") for (int g = 0; g < 4; ++g)                          \
            _Pragma("unroll") for (int jj = 0; jj < 2; ++jj)                   \
                ACCN[g][jj] =                                                  \
                    MFMA_16x16x32_BF16(fw[k], bfr[g][jj][k], ACCN[g][jj],      \
                                       0, 0, 0);                               \
    /* H-MFMA(T): complete ACCC with h(T-1) */                                 \
    _Pragma("unroll") for (int k = 0; k < 4; ++k)                              \
        _Pragma("unroll") for (int g = 0; g < 4; ++g)                          \
            _Pragma("unroll") for (int jj = 0; jj < 2; ++jj)                   \
                ACCC[g][jj] =                                                  \
                    MFMA_16x16x32_BF16(fh[k], bfr[g][jj][4 + k], ACCC[g][jj],  \
                                       0, 0, 0);                               \
    /* stage w_in(T+2) -> wbuf[SW]; prefetch x(T+4) */                         \
    {                                                                          \
      u32x4 u;                                                                 \
      u[0] = cvt_pk_bf16(XV0.x * at0.x, XV0.y * at0.y);                        \
      u[1] = cvt_pk_bf16(XV0.z * at0.z, XV0.w * at0.w);                        \
      u[2] = cvt_pk_bf16(XV1.x * at1.x, XV1.y * at1.y);                        \
      u[3] = cvt_pk_bf16(XV1.z * at1.z, XV1.w * at1.w);                        \
      *reinterpret_cast<u32x4*>(stgW + (SW)) = u;                              \
    }                                                                          \
    XV0 = *reinterpret_cast<const float4*>(xrow + (((T) + 4) & 63) * 128);     \
    XV1 = *reinterpret_cast<const float4*>(xrow + (((T) + 4) & 63) * 128 + 4); \
    /* EW(T): 8 cells/lane, pre-scaled & biased acc -> direct exp2 */          \
    float h4[2][4];                                                            \
    _Pragma("unroll") for (int jj = 0; jj < 2; ++jj)                           \
        _Pragma("unroll") for (int rr = 0; rr < 4; ++rr) {                     \
      const float Ei = fexp2(ACCC[0][jj][rr]);                                 \
      const float Ef = fexp2(ACCC[1][jj][rr]);                                 \
      const float G  = fexp2(ACCC[2][jj][rr]);                                 \
      const float Eo = fexp2(ACCC[3][jj][rr]);                                 \
      const float a1 = 1.f + Ei, a2 = 1.f + Ef, a3 = G + 1.f, a4 = G - 1.f;    \
      const float m1 = a1 * a3;                                                \
      const float cn = fmaf(a2, a4, c4[jj][rr] * m1) * RCP(a2 * m1);           \
      c4[jj][rr] = cn;                                                         \
      const float C2 = fexp2(fminf(cn * L2E2, 30.f));                          \
      h4[jj][rr] = (C2 - 1.f) * RCP((1.f + Eo) * (C2 + 1.f));                  \
    }                                                                          \
    /* h(T) -> hbuf[WH], then fire-forget out stores */                        \
    _Pragma("unroll") for (int jj = 0; jj < 2; ++jj) {                         \
      const unsigned int r01 = cvt_pk_bf16(h4[jj][0], h4[jj][1]);              \
      const unsigned int r23 = cvt_pk_bf16(h4[jj][2], h4[jj][3]);              \
      *reinterpret_cast<unsigned short*>(hw[jj][0] + (WH)) =                   \
          (unsigned short)r01;                                                 \
      *reinterpret_cast<unsigned short*>(hw[jj][1] + (WH)) =                   \
          (unsigned short)(r01 >> 16);                                         \
      *reinterpret_cast<unsigned short*>(hw[jj][2] + (WH)) =                   \
          (unsigned short)r23;                                                 \
      *reinterpret_cast<unsigned short*>(hw[jj][3] + (WH)) =                   \
          (unsigned short)(r23 >> 16);                                         \
    }                                                                          \
    _Pragma("unroll") for (int jj = 0; jj < 2; ++jj)                           \
        _Pragma("unroll") for (int rr = 0; rr < 4; ++rr)                       \
            outP[(size_t)rr * 8192 + jj * 16] = h4[jj][rr];                    \
    outP += 128;                                                               \
    lds_barrier();                                                             \
  }

  for (int tt = 0; tt < 32; ++tt) {
    const int t0 = tt * 2;
    // even: read w_in(t+1)@wbuf1, h(t-1)@hbuf1; stage->wbuf0; h->hbuf0
    STEP(t0, accA, accB, 4096, 4096, 0, 0, xE0, xE1);
    // odd: read w_in(t+1)@wbuf0, h(t-1)@hbuf0; stage->wbuf1; h->hbuf1
    STEP(t0 + 1, accB, accA, 0, 0, 4096, 4096, xO0, xO1);
  }
#undef STEP
}

extern "C" void kernel_launch(void* const* d_in, const int* in_sizes, int n_in,
                              void* d_out, int out_size, void* d_ws, size_t ws_size,
                              hipStream_t stream) {
  const float* x     = (const float*)d_in[0];  // (4096, 64, 128)
  const float* W_ih  = (const float*)d_in[1];  // (512, 128)
  const float* W_hh  = (const float*)d_in[2];  // (512, 128)
  const float* b_ih  = (const float*)d_in[3];  // (512,)
  const float* b_hh  = (const float*)d_in[4];  // (512,)
  const float* Wattn = (const float*)d_in[5];  // (1, 320)
  float* out = (float*)d_out;                  // (4096, 64, 128)

  // workspace layout
  float* attn = (float*)d_ws;                                            // 2 MB
  unsigned short* Wc = (unsigned short*)((char*)d_ws + 4096 * 128 * 4);  // 256 KB
  float* biasC = (float*)((char*)d_ws + 4096 * 128 * 4 + 512 * 256 * 2); // 2 KB

  pack_kernel<<<128, 256, 0, stream>>>(W_ih, W_hh, b_ih, b_hh, Wc, biasC);
  attn_kernel<<<4096, 64, 0, stream>>>(x, Wattn, attn);
  lstm_kernel<<<256, 256, 0, stream>>>(x, Wc, biasC, attn, out);
}

// Round 13
// 111.188 us; speedup vs baseline: 1.1338x; 1.1338x over previous
//
#include <hip/hip_runtime.h>

typedef __attribute__((ext_vector_type(4))) float f32x4;
typedef __attribute__((ext_vector_type(8))) short s16x8;

#define MFMA_16x16x32_BF16 __builtin_amdgcn_mfma_f32_16x16x32_bf16

__device__ __forceinline__ unsigned short f2bf(float f) {
  unsigned int u = __builtin_bit_cast(unsigned int, f);
  unsigned int r = (u + 0x7FFFu + ((u >> 16) & 1u)) >> 16;  // RNE
  return (unsigned short)r;
}

__device__ __forceinline__ unsigned int cvt_pk_bf16(float lo, float hi) {
  unsigned int r;
  asm("v_cvt_pk_bf16_f32 %0, %1, %2" : "=v"(r) : "v"(lo), "v"(hi));
  return r;
}

__device__ __forceinline__ float fexp2(float x) {
#if __has_builtin(__builtin_amdgcn_exp2f)
  return __builtin_amdgcn_exp2f(x);
#else
  float r;
  asm("v_exp_f32 %0, %1" : "=v"(r) : "v"(x));
  return r;
#endif
}

// Fused LDS barrier: waitcnt + s_barrier in ONE asm with memory clobber.
// Leaves vmcnt (global loads/stores) in flight.
__device__ __forceinline__ void lds_barrier() {
  asm volatile("s_waitcnt lgkmcnt(0)\n\ts_barrier" ::: "memory");
}

#define RCP __builtin_amdgcn_rcpf
#define L2E 1.442695040888963f   // 1/ln2
#define L2E2 2.885390081777927f  // 2/ln2

// ---- kernel 0: pack Wc = [W_ih | W_hh] (512 x 256) -> bf16, PRE-SCALED ----
__global__ __launch_bounds__(256) void pack_kernel(
    const float* __restrict__ Wih, const float* __restrict__ Whh,
    const float* __restrict__ bih, const float* __restrict__ bhh,
    unsigned short* __restrict__ Wc, float* __restrict__ biasC) {
  int i = blockIdx.x * 256 + threadIdx.x;  // 32768 chunks of 4 elems
  int col = i >> 6;
  int k4 = (i & 63) << 2;
  const float s = ((i >> 13) == 2) ? L2E2 : -L2E;  // gate = col>>7 = i>>13
  const float* src = (k4 < 128) ? (Wih + col * 128 + k4)
                                : (Whh + col * 128 + (k4 - 128));
  const float4 v = *reinterpret_cast<const float4*>(src);
  ushort4 u;
  u.x = f2bf(v.x * s); u.y = f2bf(v.y * s);
  u.z = f2bf(v.z * s); u.w = f2bf(v.w * s);
  *reinterpret_cast<ushort4*>(Wc + (size_t)col * 256 + k4) = u;
  if (i < 512) {
    const float b = bih[i] + bhh[i];
    biasC[i] = ((i >> 7) == 2 ? L2E2 : -L2E) * b;
  }
}

// ---- kernel A: attn[b,:] = softmax_d( sum_t x[b,t,:] * wt[t] ) ----
__global__ __launch_bounds__(64) void attn_kernel(
    const float* __restrict__ x, const float* __restrict__ Wattn,
    float* __restrict__ attn) {
  const int b = blockIdx.x;
  const int l = threadIdx.x;  // 0..63
  const float* xb = x + (size_t)b * 64 * 128;
  const float wtl = Wattn[256 + l];
  float s0 = 0.f, s1 = 0.f;
  for (int t = 0; t < 64; ++t) {
    float w = __shfl(wtl, t, 64);
    s0 = fmaf(xb[t * 128 + l], w, s0);
    s1 = fmaf(xb[t * 128 + 64 + l], w, s1);
  }
  float m = fmaxf(s0, s1);
  for (int off = 32; off; off >>= 1) m = fmaxf(m, __shfl_xor(m, off, 64));
  float e0 = __expf(s0 - m), e1 = __expf(s1 - m);
  float sum = e0 + e1;
  for (int off = 32; off; off >>= 1) sum += __shfl_xor(sum, off, 64);
  float inv = RCP(sum);
  attn[(size_t)b * 128 + l] = e0 * inv;
  attn[(size_t)b * 128 + 64 + l] = e1 * inv;
}

// ---- kernel B: persistent LSTM, 2-ahead pipeline + WAVE DESYNC ----
// R11 base (best known: 88.8us). Waves 0-3: W-MFMA(T+1) then H-MFMA(T);
// waves 4-7: reversed (h-reads + H-MFMA first). Splits the post-barrier
// LDS port burst and offsets each group's EW window against the other
// group's MFMA issue -> pipes interleave across waves instead of colliding.
// LDS: wbuf0@0, wbuf1@4096, hbuf0@8192, hbuf1@12288; swizzle ^(row&7)<<4.
__global__ __launch_bounds__(512, 2) void lstm_kernel(
    const float* __restrict__ x, const unsigned short* __restrict__ Wc,
    const float* __restrict__ biasC, const float* __restrict__ attn,
    float* __restrict__ out) {
  __shared__ __attribute__((aligned(16))) char sAb[16384];

  const int tid = threadIdx.x;
  const int l = tid & 63;
  const int w = tid >> 6;   // 0..7
  const int l15 = l & 15;
  const int khi = l >> 4;   // 0..3
  const int rowBase = blockIdx.x * 16;
  // wave-group flag in SGPR (scalar branch, no exec-mask churn)
  const int wg = __builtin_amdgcn_readfirstlane(w >> 2);

  // ---- B fragments into registers (once): 4 gates x 8 kt x 16B ----
  s16x8 bfr[4][8];
  float bias2[4];
#pragma unroll
  for (int g = 0; g < 4; ++g) {
    const int col = g * 128 + w * 16 + l15;
    const unsigned short* p = Wc + (size_t)col * 256 + khi * 8;
#pragma unroll
    for (int kt = 0; kt < 8; ++kt)
      bfr[g][kt] = *reinterpret_cast<const s16x8*>(p + kt * 32);
    bias2[g] = biasC[col];
  }

  // ---- staging role: thread -> (row r_st, 4 cols at c_st) ----
  const int r_st = tid >> 5;          // 0..15
  const int c_st = (tid & 31) << 2;   // 0..124
  const float4 at =
      *reinterpret_cast<const float4*>(attn + (size_t)(rowBase + r_st) * 128 + c_st);
  const float* xrow = x + (size_t)(rowBase + r_st) * 8192 + c_st;
  char* stgW = sAb + r_st * 256 + ((c_st << 1) ^ ((r_st & 7) << 4));

  // zero hbuf1 (h(-1) = 0; iter 0 reads hbuf1)
  {
    uint2 z = {0u, 0u};
    *reinterpret_cast<uint2*>(sAb + 12288 + tid * 8) = z;
  }

  // stage w_in(0) -> wbuf0, w_in(1) -> wbuf1
  {
    const float4 x0 = *reinterpret_cast<const float4*>(xrow);
    const float4 x1 = *reinterpret_cast<const float4*>(xrow + 128);
    uint2 u0, u1;
    u0.x = cvt_pk_bf16(x0.x * at.x, x0.y * at.y);
    u0.y = cvt_pk_bf16(x0.z * at.z, x0.w * at.w);
    u1.x = cvt_pk_bf16(x1.x * at.x, x1.y * at.y);
    u1.y = cvt_pk_bf16(x1.z * at.z, x1.w * at.w);
    *reinterpret_cast<uint2*>(stgW) = u0;
    *reinterpret_cast<uint2*>(stgW + 4096) = u1;
  }
  float4 xvE = *reinterpret_cast<const float4*>(xrow + 2 * 128);  // x(2)
  float4 xvO = *reinterpret_cast<const float4*>(xrow + 3 * 128);  // x(3)

  // ---- MFMA read pointers (base = buf0; add RW/RH per parity) ----
  const char* aw[4];
  const char* ah[4];
#pragma unroll
  for (int k = 0; k < 4; ++k) {
    aw[k] = sAb + l15 * 256 + ((k * 64 + khi * 16) ^ ((l15 & 7) << 4));
    ah[k] = aw[k] + 8192;
  }
  // h-write pointers (base = hbuf0)
  char* hw[4];
#pragma unroll
  for (int rr = 0; rr < 4; ++rr) {
    const int row = khi * 4 + rr;
    hw[rr] = sAb + 8192 + row * 256 + (((w * 16 + l15) << 1) ^ ((row & 7) << 4));
  }

  float c4[4] = {0.f, 0.f, 0.f, 0.f};
  float* outP = out + (size_t)(rowBase + khi * 4) * 8192 + w * 16 + l15;

  lds_barrier();

  // pre-loop: accA = bias + W-part(0) (reads wbuf0)
  f32x4 accA[4], accB[4];
#pragma unroll
  for (int g = 0; g < 4; ++g)
    accA[g] = f32x4{bias2[g], bias2[g], bias2[g], bias2[g]};
#pragma unroll
  for (int k = 0; k < 4; ++k) {
    const s16x8 af = *reinterpret_cast<const s16x8*>(aw[k]);
#pragma unroll
    for (int g = 0; g < 4; ++g)
      accA[g] = MFMA_16x16x32_BF16(af, bfr[g][k], accA[g], 0, 0, 0);
  }

  lds_barrier();  // close pre-loop wbuf0 reads before STEP0 restages it

#define STEP(T, ACCC, ACCN, RW, RH, SW, WH, XVS)                               \
  {                                                                            \
    s16x8 fw[4], fh[4];                                                        \
    _Pragma("unroll") for (int g = 0; g < 4; ++g)                              \
        ACCN[g] = f32x4{bias2[g], bias2[g], bias2[g], bias2[g]};               \
    if (wg) {                                                                  \
      /* waves 4-7: H-first (eat fresh-h latency while group 0 issues W) */    \
      _Pragma("unroll") for (int k = 0; k < 4; ++k)                            \
          fh[k] = *reinterpret_cast<const s16x8*>(ah[k] + (RH));               \
      _Pragma("unroll") for (int k = 0; k < 4; ++k)                            \
          fw[k] = *reinterpret_cast<const s16x8*>(aw[k] + (RW));               \
      __builtin_amdgcn_s_setprio(1);                                           \
      _Pragma("unroll") for (int k = 0; k < 4; ++k) {                          \
        _Pragma("unroll") for (int g = 0; g < 4; ++g)                          \
            ACCC[g] = MFMA_16x16x32_BF16(fh[k], bfr[g][4 + k], ACCC[g],        \
                                         0, 0, 0);                             \
      }                                                                        \
      _Pragma("unroll") for (int k = 0; k < 4; ++k) {                          \
        _Pragma("unroll") for (int g = 0; g < 4; ++g)                          \
            ACCN[g] = MFMA_16x16x32_BF16(fw[k], bfr[g][k], ACCN[g],            \
                                         0, 0, 0);                             \
      }                                                                        \
      __builtin_amdgcn_s_setprio(0);                                           \
    } else {                                                                   \
      /* waves 0-3: W-first (stable wbuf, no wait) */                          \
      _Pragma("unroll") for (int k = 0; k < 4; ++k)                            \
          fw[k] = *reinterpret_cast<const s16x8*>(aw[k] + (RW));               \
      _Pragma("unroll") for (int k = 0; k < 4; ++k)                            \
          fh[k] = *reinterpret_cast<const s16x8*>(ah[k] + (RH));               \
      __builtin_amdgcn_s_setprio(1);                                           \
      _Pragma("unroll") for (int k = 0; k < 4; ++k) {                          \
        _Pragma("unroll") for (int g = 0; g < 4; ++g)                          \
            ACCN[g] = MFMA_16x16x32_BF16(fw[k], bfr[g][k], ACCN[g],            \
                                         0, 0, 0);                             \
      }                                                                        \
      _Pragma("unroll") for (int k = 0; k < 4; ++k) {                          \
        _Pragma("unroll") for (int g = 0; g < 4; ++g)                          \
            ACCC[g] = MFMA_16x16x32_BF16(fh[k], bfr[g][4 + k], ACCC[g],        \
                                         0, 0, 0);                             \
      }                                                                        \
      __builtin_amdgcn_s_setprio(0);                                           \
    }                                                                          \
    /* stage w_in(T+2); prefetch x(T+4) */                                     \
    {                                                                          \
      uint2 u;                                                                 \
      u.x = cvt_pk_bf16(XVS.x * at.x, XVS.y * at.y);                           \
      u.y = cvt_pk_bf16(XVS.z * at.z, XVS.w * at.w);                           \
      *reinterpret_cast<uint2*>(stgW + (SW)) = u;                              \
    }                                                                          \
    XVS = *reinterpret_cast<const float4*>(xrow + (((T) + 4) & 63) * 128);     \
    /* EW(T): pre-scaled & biased acc -> direct exp2 (C2 guard only) */        \
    float h4[4];                                                               \
    _Pragma("unroll") for (int rr = 0; rr < 4; ++rr) {                         \
      const float Ei = fexp2(ACCC[0][rr]);                                     \
      const float Ef = fexp2(ACCC[1][rr]);                                     \
      const float G  = fexp2(ACCC[2][rr]);                                     \
      const float Eo = fexp2(ACCC[3][rr]);                                     \
      const float a1 = 1.f + Ei, a2 = 1.f + Ef, a3 = G + 1.f, a4 = G - 1.f;    \
      const float m1 = a1 * a3;                                                \
      const float cn = fmaf(a2, a4, c4[rr] * m1) * RCP(a2 * m1);               \
      c4[rr] = cn;                                                             \
      const float C2 = fexp2(fminf(cn * L2E2, 30.f));                          \
      h4[rr] = (C2 - 1.f) * RCP((1.f + Eo) * (C2 + 1.f));                      \
    }                                                                          \
    /* h(T) -> hbuf[WH] first, then fire-forget out stores */                  \
    {                                                                          \
      const unsigned int r01 = cvt_pk_bf16(h4[0], h4[1]);                      \
      const unsigned int r23 = cvt_pk_bf16(h4[2], h4[3]);                      \
      *reinterpret_cast<unsigned short*>(hw[0] + (WH)) = (unsigned short)r01;  \
      *reinterpret_cast<unsigned short*>(hw[1] + (WH)) =                       \
          (unsigned short)(r01 >> 16);                                         \
      *reinterpret_cast<unsigned short*>(hw[2] + (WH)) = (unsigned short)r23;  \
      *reinterpret_cast<unsigned short*>(hw[3] + (WH)) =                       \
          (unsigned short)(r23 >> 16);                                         \
    }                                                                          \
    _Pragma("unroll") for (int rr = 0; rr < 4; ++rr)                           \
        outP[(size_t)rr * 8192] = h4[rr];                                      \
    outP += 128;                                                               \
    lds_barrier();                                                             \
  }

  for (int tt = 0; tt < 32; ++tt) {
    const int t0 = tt * 2;
    // even: read w_in(t+1)@wbuf1, h(t-1)@hbuf1; stage->wbuf0; h->hbuf0
    STEP(t0, accA, accB, 4096, 4096, 0, 0, xvE);
    // odd: read w_in(t+1)@wbuf0, h(t-1)@hbuf0; stage->wbuf1; h->hbuf1
    STEP(t0 + 1, accB, accA, 0, 0, 4096, 4096, xvO);
  }
#undef STEP
}

extern "C" void kernel_launch(void* const* d_in, const int* in_sizes, int n_in,
                              void* d_out, int out_size, void* d_ws, size_t ws_size,
                              hipStream_t stream) {
  const float* x     = (const float*)d_in[0];  // (4096, 64, 128)
  const float* W_ih  = (const float*)d_in[1];  // (512, 128)
  const float* W_hh  = (const float*)d_in[2];  // (512, 128)
  const float* b_ih  = (const float*)d_in[3];  // (512,)
  const float* b_hh  = (const float*)d_in[4];  // (512,)
  const float* Wattn = (const float*)d_in[5];  // (1, 320)
  float* out = (float*)d_out;                  // (4096, 64, 128)

  // workspace layout
  float* attn = (float*)d_ws;                                            // 2 MB
  unsigned short* Wc = (unsigned short*)((char*)d_ws + 4096 * 128 * 4);  // 256 KB
  float* biasC = (float*)((char*)d_ws + 4096 * 128 * 4 + 512 * 256 * 2); // 2 KB

  pack_kernel<<<128, 256, 0, stream>>>(W_ih, W_hh, b_ih, b_hh, Wc, biasC);
  attn_kernel<<<4096, 64, 0, stream>>>(x, Wattn, attn);
  lstm_kernel<<<256, 512, 0, stream>>>(x, Wc, biasC, attn, out);
}

// Round 14
// 102.654 us; speedup vs baseline: 1.2281x; 1.0831x over previous
//
#include <hip/hip_runtime.h>

typedef __attribute__((ext_vector_type(4))) float f32x4;
typedef __attribute__((ext_vector_type(8))) short s16x8;

#define MFMA_16x16x32_BF16 __builtin_amdgcn_mfma_f32_16x16x32_bf16

__device__ __forceinline__ unsigned short f2bf(float f) {
  unsigned int u = __builtin_bit_cast(unsigned int, f);
  unsigned int r = (u + 0x7FFFu + ((u >> 16) & 1u)) >> 16;  // RNE
  return (unsigned short)r;
}

__device__ __forceinline__ unsigned int cvt_pk_bf16(float lo, float hi) {
  unsigned int r;
  asm("v_cvt_pk_bf16_f32 %0, %1, %2" : "=v"(r) : "v"(lo), "v"(hi));
  return r;
}

__device__ __forceinline__ float fexp2(float x) {
#if __has_builtin(__builtin_amdgcn_exp2f)
  return __builtin_amdgcn_exp2f(x);
#else
  float r;
  asm("v_exp_f32 %0, %1" : "=v"(r) : "v"(x));
  return r;
#endif
}

// Fused LDS barrier: waitcnt + s_barrier in ONE asm with memory clobber.
// Leaves vmcnt (global loads/stores) in flight.
__device__ __forceinline__ void lds_barrier() {
  asm volatile("s_waitcnt lgkmcnt(0)\n\ts_barrier" ::: "memory");
}

#define RCP __builtin_amdgcn_rcpf
#define L2E 1.442695040888963f   // 1/ln2
#define L2E2 2.885390081777927f  // 2/ln2

// ---- kernel A+0: attn softmax (vectorized) + weight pack, one launch ----
// Grid 4096 x 64. Each block: attn row b via float4 loads (lane halves split
// even/odd t -> 1KB contiguous per iter), softmax over d. Threads 0-7 also
// pack 8 chunks of Wc (b*8+l of 32768) with gate pre-scale, and biasC.
__global__ __launch_bounds__(64) void attn_pack_kernel(
    const float* __restrict__ x, const float* __restrict__ Wattn,
    const float* __restrict__ Wih, const float* __restrict__ Whh,
    const float* __restrict__ bih, const float* __restrict__ bhh,
    float* __restrict__ attn, unsigned short* __restrict__ Wc,
    float* __restrict__ biasC) {
  const int b = blockIdx.x;
  const int l = threadIdx.x;   // 0..63
  const int th = l >> 5;       // t-parity half
  const int cl = l & 31;       // col group (4 cols)

  // ---- pack: 8 chunks per block (threads 0-7) ----
  if (l < 8) {
    const int i = b * 8 + l;          // 0..32767
    const int col = i >> 6;
    const int k4 = (i & 63) << 2;
    const float s = ((i >> 13) == 2) ? L2E2 : -L2E;
    const float* src = (k4 < 128) ? (Wih + col * 128 + k4)
                                  : (Whh + col * 128 + (k4 - 128));
    const float4 v = *reinterpret_cast<const float4*>(src);
    ushort4 u;
    u.x = f2bf(v.x * s); u.y = f2bf(v.y * s);
    u.z = f2bf(v.z * s); u.w = f2bf(v.w * s);
    *reinterpret_cast<ushort4*>(Wc + (size_t)col * 256 + k4) = u;
    if (i < 512) {
      const float bb = bih[i] + bhh[i];
      biasC[i] = ((i >> 7) == 2 ? L2E2 : -L2E) * bb;
    }
  }

  // ---- attn: s[cl*4..+3] = sum_t x[b,t,:]*wt[t], float4 loads ----
  const float wtl = Wattn[256 + l];  // lane l holds wt[l]
  const float* xp = x + (size_t)b * 8192 + cl * 4;
  float4 s4 = {0.f, 0.f, 0.f, 0.f};
  for (int it = 0; it < 32; ++it) {
    const int t = it * 2 + th;
    const float ww = __shfl(wtl, t, 64);
    const float4 v = *reinterpret_cast<const float4*>(xp + t * 128);
    s4.x = fmaf(v.x, ww, s4.x); s4.y = fmaf(v.y, ww, s4.y);
    s4.z = fmaf(v.z, ww, s4.z); s4.w = fmaf(v.w, ww, s4.w);
  }
  // combine halves (both halves end up with the full sum)
  s4.x += __shfl_xor(s4.x, 32, 64);
  s4.y += __shfl_xor(s4.y, 32, 64);
  s4.z += __shfl_xor(s4.z, 32, 64);
  s4.w += __shfl_xor(s4.w, 32, 64);
  // softmax over d (reduce across the 32-lane group)
  float m = fmaxf(fmaxf(s4.x, s4.y), fmaxf(s4.z, s4.w));
#pragma unroll
  for (int off = 16; off; off >>= 1) m = fmaxf(m, __shfl_xor(m, off, 64));
  const float e0 = __expf(s4.x - m), e1 = __expf(s4.y - m);
  const float e2 = __expf(s4.z - m), e3 = __expf(s4.w - m);
  float sum = (e0 + e1) + (e2 + e3);
#pragma unroll
  for (int off = 16; off; off >>= 1) sum += __shfl_xor(sum, off, 64);
  const float inv = RCP(sum);
  if (th == 0) {
    float4 o = {e0 * inv, e1 * inv, e2 * inv, e3 * inv};
    *reinterpret_cast<float4*>(attn + (size_t)b * 128 + cl * 4) = o;
  }
}

// ---- kernel B: persistent LSTM, 2-ahead pipeline (R11 verbatim) ----
// 512 thr = 8 waves, 16 rows/block, grid 256 (1 block/CU; bfr=128 VGPR/wave).
// Per step: W-MFMA(T+1) first (stable wbuf hides fresh h-frag ds latency),
// H-MFMA(T), stage w_in(T+2), EW(T) (exp2 direct, C2 guard only),
// h->LDS, fire-forget out-stores, ONE fused lds_barrier.
// LDS: wbuf0@0, wbuf1@4096, hbuf0@8192, hbuf1@12288; swizzle ^(row&7)<<4.
__global__ __launch_bounds__(512, 2) void lstm_kernel(
    const float* __restrict__ x, const unsigned short* __restrict__ Wc,
    const float* __restrict__ biasC, const float* __restrict__ attn,
    float* __restrict__ out) {
  __shared__ __attribute__((aligned(16))) char sAb[16384];

  const int tid = threadIdx.x;
  const int l = tid & 63;
  const int w = tid >> 6;   // 0..7
  const int l15 = l & 15;
  const int khi = l >> 4;   // 0..3
  const int rowBase = blockIdx.x * 16;

  // ---- B fragments into registers (once): 4 gates x 8 kt x 16B ----
  s16x8 bfr[4][8];
  float bias2[4];
#pragma unroll
  for (int g = 0; g < 4; ++g) {
    const int col = g * 128 + w * 16 + l15;
    const unsigned short* p = Wc + (size_t)col * 256 + khi * 8;
#pragma unroll
    for (int kt = 0; kt < 8; ++kt)
      bfr[g][kt] = *reinterpret_cast<const s16x8*>(p + kt * 32);
    bias2[g] = biasC[col];
  }

  // ---- staging role: thread -> (row r_st, 4 cols at c_st) ----
  const int r_st = tid >> 5;          // 0..15
  const int c_st = (tid & 31) << 2;   // 0..124
  const float4 at =
      *reinterpret_cast<const float4*>(attn + (size_t)(rowBase + r_st) * 128 + c_st);
  const float* xrow = x + (size_t)(rowBase + r_st) * 8192 + c_st;
  char* stgW = sAb + r_st * 256 + ((c_st << 1) ^ ((r_st & 7) << 4));

  // zero hbuf1 (h(-1) = 0; iter 0 reads hbuf1)
  {
    uint2 z = {0u, 0u};
    *reinterpret_cast<uint2*>(sAb + 12288 + tid * 8) = z;
  }

  // stage w_in(0) -> wbuf0, w_in(1) -> wbuf1
  {
    const float4 x0 = *reinterpret_cast<const float4*>(xrow);
    const float4 x1 = *reinterpret_cast<const float4*>(xrow + 128);
    uint2 u0, u1;
    u0.x = cvt_pk_bf16(x0.x * at.x, x0.y * at.y);
    u0.y = cvt_pk_bf16(x0.z * at.z, x0.w * at.w);
    u1.x = cvt_pk_bf16(x1.x * at.x, x1.y * at.y);
    u1.y = cvt_pk_bf16(x1.z * at.z, x1.w * at.w);
    *reinterpret_cast<uint2*>(stgW) = u0;
    *reinterpret_cast<uint2*>(stgW + 4096) = u1;
  }
  float4 xvE = *reinterpret_cast<const float4*>(xrow + 2 * 128);  // x(2)
  float4 xvO = *reinterpret_cast<const float4*>(xrow + 3 * 128);  // x(3)

  // ---- MFMA read pointers (base = buf0; add RW/RH per parity) ----
  const char* aw[4];
  const char* ah[4];
#pragma unroll
  for (int k = 0; k < 4; ++k) {
    aw[k] = sAb + l15 * 256 + ((k * 64 + khi * 16) ^ ((l15 & 7) << 4));
    ah[k] = aw[k] + 8192;
  }
  // h-write pointers (base = hbuf0)
  char* hw[4];
#pragma unroll
  for (int rr = 0; rr < 4; ++rr) {
    const int row = khi * 4 + rr;
    hw[rr] = sAb + 8192 + row * 256 + (((w * 16 + l15) << 1) ^ ((row & 7) << 4));
  }

  float c4[4] = {0.f, 0.f, 0.f, 0.f};
  float* outP = out + (size_t)(rowBase + khi * 4) * 8192 + w * 16 + l15;

  lds_barrier();

  // pre-loop: accA = bias + W-part(0) (reads wbuf0)
  f32x4 accA[4], accB[4];
#pragma unroll
  for (int g = 0; g < 4; ++g)
    accA[g] = f32x4{bias2[g], bias2[g], bias2[g], bias2[g]};
#pragma unroll
  for (int k = 0; k < 4; ++k) {
    const s16x8 af = *reinterpret_cast<const s16x8*>(aw[k]);
#pragma unroll
    for (int g = 0; g < 4; ++g)
      accA[g] = MFMA_16x16x32_BF16(af, bfr[g][k], accA[g], 0, 0, 0);
  }

  lds_barrier();  // close pre-loop wbuf0 reads before STEP0 restages it

#define STEP(T, ACCC, ACCN, RW, RH, SW, WH, XVS)                               \
  {                                                                            \
    __builtin_amdgcn_s_setprio(1);                                             \
    /* W-MFMA(T+1) into ACCN FIRST: wbuf data is a step old (no wait);     */  \
    /* its issue hides the fresh h-frag ds_read latency.                   */  \
    _Pragma("unroll") for (int g = 0; g < 4; ++g)                              \
        ACCN[g] = f32x4{bias2[g], bias2[g], bias2[g], bias2[g]};               \
    _Pragma("unroll") for (int k = 0; k < 4; ++k) {                            \
      const s16x8 af = *reinterpret_cast<const s16x8*>(aw[k] + (RW));          \
      _Pragma("unroll") for (int g = 0; g < 4; ++g)                            \
          ACCN[g] = MFMA_16x16x32_BF16(af, bfr[g][k], ACCN[g], 0, 0, 0);       \
    }                                                                          \
    /* H-MFMA(T): complete ACCC with h(T-1) */                                 \
    _Pragma("unroll") for (int k = 0; k < 4; ++k) {                            \
      const s16x8 af = *reinterpret_cast<const s16x8*>(ah[k] + (RH));          \
      _Pragma("unroll") for (int g = 0; g < 4; ++g)                            \
          ACCC[g] = MFMA_16x16x32_BF16(af, bfr[g][4 + k], ACCC[g], 0, 0, 0);   \
    }                                                                          \
    __builtin_amdgcn_s_setprio(0);                                             \
    /* stage w_in(T+2); prefetch x(T+4) */                                     \
    {                                                                          \
      uint2 u;                                                                 \
      u.x = cvt_pk_bf16(XVS.x * at.x, XVS.y * at.y);                           \
      u.y = cvt_pk_bf16(XVS.z * at.z, XVS.w * at.w);                           \
      *reinterpret_cast<uint2*>(stgW + (SW)) = u;                              \
    }                                                                          \
    XVS = *reinterpret_cast<const float4*>(xrow + (((T) + 4) & 63) * 128);     \
    /* EW(T): pre-scaled & biased acc -> direct exp2 (C2 guard only) */        \
    float h4[4];                                                               \
    _Pragma("unroll") for (int rr = 0; rr < 4; ++rr) {                         \
      const float Ei = fexp2(ACCC[0][rr]);                                     \
      const float Ef = fexp2(ACCC[1][rr]);                                     \
      const float G  = fexp2(ACCC[2][rr]);                                     \
      const float Eo = fexp2(ACCC[3][rr]);                                     \
      const float a1 = 1.f + Ei, a2 = 1.f + Ef, a3 = G + 1.f, a4 = G - 1.f;    \
      const float m1 = a1 * a3;                                                \
      const float cn = fmaf(a2, a4, c4[rr] * m1) * RCP(a2 * m1);               \
      c4[rr] = cn;                                                             \
      const float C2 = fexp2(fminf(cn * L2E2, 30.f));                          \
      h4[rr] = (C2 - 1.f) * RCP((1.f + Eo) * (C2 + 1.f));                      \
    }                                                                          \
    /* h(T) -> hbuf[WH] FIRST (producer tail), then fire-forget stores */      \
    {                                                                          \
      const unsigned int r01 = cvt_pk_bf16(h4[0], h4[1]);                      \
      const unsigned int r23 = cvt_pk_bf16(h4[2], h4[3]);                      \
      *reinterpret_cast<unsigned short*>(hw[0] + (WH)) = (unsigned short)r01;  \
      *reinterpret_cast<unsigned short*>(hw[1] + (WH)) =                       \
          (unsigned short)(r01 >> 16);                                         \
      *reinterpret_cast<unsigned short*>(hw[2] + (WH)) = (unsigned short)r23;  \
      *reinterpret_cast<unsigned short*>(hw[3] + (WH)) =                       \
          (unsigned short)(r23 >> 16);                                         \
    }                                                                          \
    _Pragma("unroll") for (int rr = 0; rr < 4; ++rr)                           \
        outP[(size_t)rr * 8192] = h4[rr];                                      \
    outP += 128;                                                               \
    lds_barrier();                                                             \
  }

  for (int tt = 0; tt < 32; ++tt) {
    const int t0 = tt * 2;
    // even: read w_in(t+1)@wbuf1, h(t-1)@hbuf1; stage->wbuf0; h->hbuf0
    STEP(t0, accA, accB, 4096, 4096, 0, 0, xvE);
    // odd: read w_in(t+1)@wbuf0, h(t-1)@hbuf0; stage->wbuf1; h->hbuf1
    STEP(t0 + 1, accB, accA, 0, 0, 4096, 4096, xvO);
  }
#undef STEP
}

extern "C" void kernel_launch(void* const* d_in, const int* in_sizes, int n_in,
                              void* d_out, int out_size, void* d_ws, size_t ws_size,
                              hipStream_t stream) {
  const float* x     = (const float*)d_in[0];  // (4096, 64, 128)
  const float* W_ih  = (const float*)d_in[1];  // (512, 128)
  const float* W_hh  = (const float*)d_in[2];  // (512, 128)
  const float* b_ih  = (const float*)d_in[3];  // (512,)
  const float* b_hh  = (const float*)d_in[4];  // (512,)
  const float* Wattn = (const float*)d_in[5];  // (1, 320)
  float* out = (float*)d_out;                  // (4096, 64, 128)

  // workspace layout
  float* attn = (float*)d_ws;                                            // 2 MB
  unsigned short* Wc = (unsigned short*)((char*)d_ws + 4096 * 128 * 4);  // 256 KB
  float* biasC = (float*)((char*)d_ws + 4096 * 128 * 4 + 512 * 256 * 2); // 2 KB

  attn_pack_kernel<<<4096, 64, 0, stream>>>(x, Wattn, W_ih, W_hh, b_ih, b_hh,
                                            attn, Wc, biasC);
  lstm_kernel<<<256, 512, 0, stream>>>(x, Wc, biasC, attn, out);
}